// Round 1
// baseline (372.793 us; speedup 1.0000x reference)
//
#include <hip/hip_runtime.h>
#include <math.h>

#define F 128
#define DEG 5
#define TN 64
#define MAXNORM_D 0.996          // (1 - 4e-3)/sqrt(c), c=1
#define MIN_NORM_D 1e-15

__device__ inline double atanh_clip(double v) {
    v = fmin(fmax(v, -1.0 + 1e-7), 1.0 - 1e-7);
    return atanh(v);
}

// ---------------------------------------------------------------- K1: in-degree histogram of dst
__global__ __launch_bounds__(256) void k_hist(const int* __restrict__ edge, int* __restrict__ cnt, int E) {
    int e = blockIdx.x * 256 + threadIdx.x;
    if (e < E) atomicAdd(&cnt[edge[E + e]], 1);
}

// ---------------------------------------------------------------- K2: y = x @ W^T  [N,128]
// Fused: ssum2[f] += sum_n y[n,f]^2 ; wsum2[f] += sum_n cnt[n]*y[n,f]^2
// Block: 256 threads, 64-node tile, micro-tile 4f x 8n per thread, k chunked by 64.
__global__ __launch_bounds__(256) void k_gemm(const float* __restrict__ x, const float* __restrict__ W,
                                              const int* __restrict__ cnt, float* __restrict__ y,
                                              float* __restrict__ ssum2, float* __restrict__ wsum2, int N) {
    __shared__ float WT[64 * 132];   // WT[k][f], padded row 132 (16B-aligned, conflict-free)
    __shared__ float XT[64 * 68];    // XT[k][n], padded row 68
    __shared__ float red_ss[F];
    __shared__ float red_ws[F];
    __shared__ int cntL[TN];

    int t = threadIdx.x;
    int n0 = blockIdx.x * TN;

    if (t < F) { red_ss[t] = 0.f; red_ws[t] = 0.f; }
    if (t < TN) { int n = n0 + t; cntL[t] = (n < N) ? cnt[n] : 0; }

    float4 acc[8];
#pragma unroll
    for (int j = 0; j < 8; j++) acc[j] = make_float4(0.f, 0.f, 0.f, 0.f);

    int f0 = (t & 31) * 4;       // 4 consecutive f
    int nb = (t >> 5) * 8;       // 8 consecutive local n

    for (int kc = 0; kc < F; kc += 64) {
        __syncthreads();
        // stage W chunk: 128f x 64k -> WT[k][f]
#pragma unroll
        for (int i = 0; i < 8; i++) {
            int id = t + 256 * i;
            int fr = id & 127;
            int kq = id >> 7;   // 0..15
            float4 w4 = *(const float4*)&W[fr * F + kc + kq * 4];
            WT[(kq * 4 + 0) * 132 + fr] = w4.x;
            WT[(kq * 4 + 1) * 132 + fr] = w4.y;
            WT[(kq * 4 + 2) * 132 + fr] = w4.z;
            WT[(kq * 4 + 3) * 132 + fr] = w4.w;
        }
        // stage x chunk: 64n x 64k -> XT[k][n]
#pragma unroll
        for (int i = 0; i < 4; i++) {
            int id = t + 256 * i;
            int nl = id & 63;
            int kq = id >> 6;   // 0..15
            int n = n0 + nl;
            float4 xv = (n < N) ? *(const float4*)&x[(size_t)n * F + kc + kq * 4]
                                : make_float4(0.f, 0.f, 0.f, 0.f);
            XT[(kq * 4 + 0) * 68 + nl] = xv.x;
            XT[(kq * 4 + 1) * 68 + nl] = xv.y;
            XT[(kq * 4 + 2) * 68 + nl] = xv.z;
            XT[(kq * 4 + 3) * 68 + nl] = xv.w;
        }
        __syncthreads();
#pragma unroll 4
        for (int k = 0; k < 64; k++) {
            float4 w4 = *(const float4*)&WT[k * 132 + f0];
            float4 xa = *(const float4*)&XT[k * 68 + nb];
            float4 xb = *(const float4*)&XT[k * 68 + nb + 4];
#define FMA4(A, S) A.x = fmaf(w4.x, S, A.x); A.y = fmaf(w4.y, S, A.y); \
                   A.z = fmaf(w4.z, S, A.z); A.w = fmaf(w4.w, S, A.w)
            FMA4(acc[0], xa.x); FMA4(acc[1], xa.y); FMA4(acc[2], xa.z); FMA4(acc[3], xa.w);
            FMA4(acc[4], xb.x); FMA4(acc[5], xb.y); FMA4(acc[6], xb.z); FMA4(acc[7], xb.w);
#undef FMA4
        }
    }

    // store y (coalesced float4 rows)
#pragma unroll
    for (int j = 0; j < 8; j++) {
        int n = n0 + nb + j;
        if (n < N) *(float4*)&y[(size_t)n * F + f0] = acc[j];
    }
    // per-thread partial column sums of squares
    float ssv[4] = {0.f, 0.f, 0.f, 0.f};
    float wsv[4] = {0.f, 0.f, 0.f, 0.f};
#pragma unroll
    for (int j = 0; j < 8; j++) {
        float c = (float)cntL[nb + j];
        float4 v = acc[j];
        ssv[0] += v.x * v.x; ssv[1] += v.y * v.y; ssv[2] += v.z * v.z; ssv[3] += v.w * v.w;
        wsv[0] += c * v.x * v.x; wsv[1] += c * v.y * v.y; wsv[2] += c * v.z * v.z; wsv[3] += c * v.w * v.w;
    }
#pragma unroll
    for (int i = 0; i < 4; i++) {
        atomicAdd(&red_ss[f0 + i], ssv[i]);
        atomicAdd(&red_ws[f0 + i], wsv[i]);
    }
    __syncthreads();
    if (t < F) {
        atomicAdd(&ssum2[t], red_ss[t]);
        atomicAdd(&wsum2[t], red_ws[t]);
    }
}

// ---------------------------------------------------------------- K2b: all global scalar factors (f64)
__global__ __launch_bounds__(256) void k_scalars(const float* __restrict__ W, const float* __restrict__ a,
                                                 const float* __restrict__ ssum2, const float* __restrict__ wsum2,
                                                 float* __restrict__ s_arr, float* __restrict__ asrc,
                                                 float* __restrict__ adst, double* __restrict__ an_out) {
    int t = threadIdx.x;
    // ||a|| over 2F = 256 elements (exactly blockDim)
    double av = (double)a[t];
    av *= av;
#pragma unroll
    for (int off = 32; off; off >>= 1) av += __shfl_down(av, off, 64);
    __shared__ double wred[4];
    if ((t & 63) == 0) wred[t >> 6] = av;
    __syncthreads();
    double an = fmax(sqrt(wred[0] + wred[1] + wred[2] + wred[3]), MIN_NORM_D);
    if (t == 0) an_out[0] = an;

    if (t < F) {
        // stage 1: h = logmap0(proj(mobius_matvec(x, W)))  row-scalar s[f]
        double wn2 = 0.0;
        for (int k = 0; k < F; k++) { double w = (double)W[t * F + k]; wn2 += w * w; }
        double wn = fmax(sqrt(wn2), MIN_NORM_D);
        double mxnf = fmax(sqrt((double)ssum2[t]), MIN_NORM_D);
        double tt = tanh(mxnf / wn * atanh_clip(wn));
        double rn = fmax(tt, MIN_NORM_D);
        double pf = (rn > MAXNORM_D) ? MAXNORM_D / rn : 1.0;
        double pn = rn * pf;
        double s = (tt / mxnf) * pf * atanh_clip(pn) / pn;
        s_arr[t] = (float)s;

        // stage 2: edge_h = proj(expmap0(concat(h[:,src], h[:,dst])))  row-scalars
        // src rows: ||row||^2 over E = DEG * ssum2[f]  (src = repeat(arange,DEG))
        double un_s = fmax(s * sqrt((double)DEG * (double)ssum2[t]), MIN_NORM_D);
        double th_s = tanh(un_s);
        double rn2 = fmax(th_s, MIN_NORM_D);
        double pf2 = (rn2 > MAXNORM_D) ? MAXNORM_D / rn2 : 1.0;
        double q_s = s * (th_s / un_s) * pf2;
        asrc[t] = (float)((double)a[t] * q_s);
        // dst rows: ||row||^2 over E = sum_n cnt[n]*y^2 = wsum2[f]
        double un_d = fmax(s * sqrt((double)wsum2[t]), MIN_NORM_D);
        double th_d = tanh(un_d);
        double rn3 = fmax(th_d, MIN_NORM_D);
        double pf3 = (rn3 > MAXNORM_D) ? MAXNORM_D / rn3 : 1.0;
        double q_d = s * (th_d / un_d) * pf3;
        adst[t] = (float)((double)a[F + t] * q_d);
    }
}

// ---------------------------------------------------------------- K3: P[n]=dot(asrc,y[n,:]) Q[n]=dot(adst,y[n,:])
__global__ __launch_bounds__(256) void k_pq(const float* __restrict__ y, const float* __restrict__ asrc,
                                            const float* __restrict__ adst, float* __restrict__ P,
                                            float* __restrict__ Q, int N) {
    __shared__ float as4[F], ad4[F];
    int t = threadIdx.x;
    if (t < F) { as4[t] = asrc[t]; ad4[t] = adst[t]; }
    __syncthreads();
    int lane = t & 31;
    int n = blockIdx.x * 8 + (t >> 5);
    if (n < N) {
        float4 yv = *(const float4*)&y[(size_t)n * F + lane * 4];
        float4 av = *(const float4*)&as4[lane * 4];
        float4 bv = *(const float4*)&ad4[lane * 4];
        float p = yv.x * av.x + yv.y * av.y + yv.z * av.z + yv.w * av.w;
        float q = yv.x * bv.x + yv.y * bv.y + yv.z * bv.z + yv.w * bv.w;
#pragma unroll
        for (int off = 16; off; off >>= 1) {
            p += __shfl_down(p, off, 32);
            q += __shfl_down(q, off, 32);
        }
        if (lane == 0) { P[n] = p; Q[n] = q; }
    }
}

// ---------------------------------------------------------------- K4: ee_pre[e] = P[src]+Q[dst]; ||ee_pre||^2 (f64)
__global__ __launch_bounds__(256) void k_edge(const int* __restrict__ edge, const float* __restrict__ P,
                                              const float* __restrict__ Q, float* __restrict__ ee_pre,
                                              double* __restrict__ mxn2, int E) {
    int t = threadIdx.x;
    int e = blockIdx.x * 256 + t;
    double local = 0.0;
    if (e < E) {
        int s = edge[e];
        int d = edge[E + e];
        float v = P[s] + Q[d];
        ee_pre[e] = v;
        local = (double)v * (double)v;
    }
#pragma unroll
    for (int off = 32; off; off >>= 1) local += __shfl_down(local, off, 64);
    __shared__ double wsum[4];
    if ((t & 63) == 0) wsum[t >> 6] = local;
    __syncthreads();
    if (t == 0) atomicAdd(mxn2, wsum[0] + wsum[1] + wsum[2] + wsum[3]);
}

// ---------------------------------------------------------------- K6: per-node aggregate + epilogue
// block = 256 threads = 2 node-groups of 128 (one thread per feature f)
__global__ __launch_bounds__(256) void k_agg(const int* __restrict__ edge, const float* __restrict__ y,
                                             const float* __restrict__ ee_pre, const float* __restrict__ s_arr,
                                             const double* __restrict__ an_p, const double* __restrict__ mxn2_p,
                                             float* __restrict__ out, int N, int E) {
    __shared__ float gS;
    __shared__ float nrm[4];
    int t = threadIdx.x;
    if (t == 0) {
        // stage 3 scalar g: ee = logmap0(proj( tanh(mxn/an*artanh(an)) * ee_pre/mxn ))
        double an = an_p[0];
        double mxn = fmax(sqrt(mxn2_p[0]), MIN_NORM_D);
        double t2 = tanh(mxn / an * atanh_clip(an));
        double f2 = t2 / mxn;
        double rn = fmax(t2, MIN_NORM_D);
        double pf = (rn > MAXNORM_D) ? MAXNORM_D / rn : 1.0;
        double pn = rn * pf;
        gS = (float)(f2 * pf * atanh_clip(pn) / pn);
    }
    __syncthreads();
    float g = gS;
    int grp = t >> 7;        // 0..1
    int f = t & 127;
    int n = blockIdx.x * 2 + grp;

    float el = 0.f;
    if (n < N) {
        float accv = 0.f, rowsum = 0.f;
#pragma unroll
        for (int j = 0; j < DEG; j++) {
            int e = n * DEG + j;
            float eev = ee_pre[e];
            float xg = g * eev;
            float gl = 0.5f * xg * (1.f + erff(xg * 0.70710678f));
            float wj = expf(-gl);
            int d = edge[E + e];
            accv = fmaf(wj, y[(size_t)d * F + f], accv);
            rowsum += wj;
        }
        float hp = s_arr[f] * accv / rowsum;
        el = (hp > 0.f) ? hp : expm1f(hp);   // elu
    }
    // norm over the 128 features of this group (2 waves)
    float ss = el * el;
#pragma unroll
    for (int off = 32; off; off >>= 1) ss += __shfl_down(ss, off, 64);
    if ((t & 63) == 0) nrm[t >> 6] = ss;
    __syncthreads();
    float sum2 = nrm[grp * 2] + nrm[grp * 2 + 1];
    if (n < N) {
        float un = fmaxf(sqrtf(sum2), 1e-15f);
        float th = tanhf(un);
        float sc = th / un;                   // expmap0
        float rn = fmaxf(th, 1e-15f);
        if (rn > 0.996f) sc *= 0.996f / rn;   // proj
        out[(size_t)n * F + f] = el * sc;
    }
}

extern "C" void kernel_launch(void* const* d_in, const int* in_sizes, int n_in,
                              void* d_out, int out_size, void* d_ws, size_t ws_size,
                              hipStream_t stream) {
    const float* x = (const float*)d_in[0];
    const int* edge = (const int*)d_in[1];
    const float* W = (const float*)d_in[2];
    const float* a = (const float*)d_in[3];
    float* out = (float*)d_out;
    int N = in_sizes[0] / F;
    int E = in_sizes[1] / 2;

    char* ws = (char*)d_ws;
    size_t off = 0;
    float* y = (float*)(ws + off);       off += (size_t)N * F * 4;
    float* ee_pre = (float*)(ws + off);  off += (size_t)E * 4;
    float* P = (float*)(ws + off);       off += (size_t)N * 4;
    float* Q = (float*)(ws + off);       off += (size_t)N * 4;
    char* zbase = ws + off;
    int* cnt = (int*)(ws + off);         off += (size_t)N * 4;
    float* ssum2 = (float*)(ws + off);   off += 512;
    float* wsum2 = (float*)(ws + off);   off += 512;
    double* mxn2 = (double*)(ws + off);  off += 8;
    size_t zlen = (size_t)((ws + off) - zbase);
    double* an_p = (double*)(ws + off);  off += 8;
    float* s_arr = (float*)(ws + off);   off += 512;
    float* asrc = (float*)(ws + off);    off += 512;
    float* adst = (float*)(ws + off);    off += 512;

    hipMemsetAsync(zbase, 0, zlen, stream);
    k_hist<<<(E + 255) / 256, 256, 0, stream>>>(edge, cnt, E);
    k_gemm<<<(N + TN - 1) / TN, 256, 0, stream>>>(x, W, cnt, y, ssum2, wsum2, N);
    k_scalars<<<1, 256, 0, stream>>>(W, a, ssum2, wsum2, s_arr, asrc, adst, an_p);
    k_pq<<<(N + 7) / 8, 256, 0, stream>>>(y, asrc, adst, P, Q, N);
    k_edge<<<(E + 255) / 256, 256, 0, stream>>>(edge, P, Q, ee_pre, mxn2, E);
    k_agg<<<(N + 1) / 2, 256, 0, stream>>>(edge, y, ee_pre, s_arr, an_p, mxn2, out, N, E);
}

// Round 2
// 328.209 us; speedup vs baseline: 1.1358x; 1.1358x over previous
//
#include <hip/hip_runtime.h>
#include <math.h>

#define F 128
#define DEG 5
#define TN 64
#define MAXNORM_D 0.996          // (1 - 4e-3)/sqrt(c), c=1
#define MIN_NORM_D 1e-15

__device__ inline double atanh_clip(double v) {
    v = fmin(fmax(v, -1.0 + 1e-7), 1.0 - 1e-7);
    return atanh(v);
}

// ---------------------------------------------------------------- K1: in-degree histogram of dst
__global__ __launch_bounds__(256) void k_hist(const int* __restrict__ edge, int* __restrict__ cnt, int E) {
    int e = blockIdx.x * 256 + threadIdx.x;
    if (e < E) atomicAdd(&cnt[edge[E + e]], 1);
}

// ---------------------------------------------------------------- K2: y = x @ W^T  [N,128]
// Fused: ssum2[f] += sum_n y[n,f]^2 ; wsum2[f] += sum_n cnt[n]*y[n,f]^2
__global__ __launch_bounds__(256) void k_gemm(const float* __restrict__ x, const float* __restrict__ W,
                                              const int* __restrict__ cnt, float* __restrict__ y,
                                              float* __restrict__ ssum2, float* __restrict__ wsum2, int N) {
    __shared__ float WT[64 * 132];   // WT[k][f], padded row 132
    __shared__ float XT[64 * 68];    // XT[k][n], padded row 68
    __shared__ float red_ss[F];
    __shared__ float red_ws[F];
    __shared__ int cntL[TN];

    int t = threadIdx.x;
    int n0 = blockIdx.x * TN;

    if (t < F) { red_ss[t] = 0.f; red_ws[t] = 0.f; }
    if (t < TN) { int n = n0 + t; cntL[t] = (n < N) ? cnt[n] : 0; }

    float4 acc[8];
#pragma unroll
    for (int j = 0; j < 8; j++) acc[j] = make_float4(0.f, 0.f, 0.f, 0.f);

    int f0 = (t & 31) * 4;       // 4 consecutive f
    int nb = (t >> 5) * 8;       // 8 consecutive local n

    for (int kc = 0; kc < F; kc += 64) {
        __syncthreads();
#pragma unroll
        for (int i = 0; i < 8; i++) {
            int id = t + 256 * i;
            int fr = id & 127;
            int kq = id >> 7;   // 0..15
            float4 w4 = *(const float4*)&W[fr * F + kc + kq * 4];
            WT[(kq * 4 + 0) * 132 + fr] = w4.x;
            WT[(kq * 4 + 1) * 132 + fr] = w4.y;
            WT[(kq * 4 + 2) * 132 + fr] = w4.z;
            WT[(kq * 4 + 3) * 132 + fr] = w4.w;
        }
#pragma unroll
        for (int i = 0; i < 4; i++) {
            int id = t + 256 * i;
            int nl = id & 63;
            int kq = id >> 6;   // 0..15
            int n = n0 + nl;
            float4 xv = (n < N) ? *(const float4*)&x[(size_t)n * F + kc + kq * 4]
                                : make_float4(0.f, 0.f, 0.f, 0.f);
            XT[(kq * 4 + 0) * 68 + nl] = xv.x;
            XT[(kq * 4 + 1) * 68 + nl] = xv.y;
            XT[(kq * 4 + 2) * 68 + nl] = xv.z;
            XT[(kq * 4 + 3) * 68 + nl] = xv.w;
        }
        __syncthreads();
#pragma unroll 4
        for (int k = 0; k < 64; k++) {
            float4 w4 = *(const float4*)&WT[k * 132 + f0];
            float4 xa = *(const float4*)&XT[k * 68 + nb];
            float4 xb = *(const float4*)&XT[k * 68 + nb + 4];
#define FMA4(A, S) A.x = fmaf(w4.x, S, A.x); A.y = fmaf(w4.y, S, A.y); \
                   A.z = fmaf(w4.z, S, A.z); A.w = fmaf(w4.w, S, A.w)
            FMA4(acc[0], xa.x); FMA4(acc[1], xa.y); FMA4(acc[2], xa.z); FMA4(acc[3], xa.w);
            FMA4(acc[4], xb.x); FMA4(acc[5], xb.y); FMA4(acc[6], xb.z); FMA4(acc[7], xb.w);
#undef FMA4
        }
    }

#pragma unroll
    for (int j = 0; j < 8; j++) {
        int n = n0 + nb + j;
        if (n < N) *(float4*)&y[(size_t)n * F + f0] = acc[j];
    }
    float ssv[4] = {0.f, 0.f, 0.f, 0.f};
    float wsv[4] = {0.f, 0.f, 0.f, 0.f};
#pragma unroll
    for (int j = 0; j < 8; j++) {
        float c = (float)cntL[nb + j];
        float4 v = acc[j];
        ssv[0] += v.x * v.x; ssv[1] += v.y * v.y; ssv[2] += v.z * v.z; ssv[3] += v.w * v.w;
        wsv[0] += c * v.x * v.x; wsv[1] += c * v.y * v.y; wsv[2] += c * v.z * v.z; wsv[3] += c * v.w * v.w;
    }
#pragma unroll
    for (int i = 0; i < 4; i++) {
        atomicAdd(&red_ss[f0 + i], ssv[i]);
        atomicAdd(&red_ws[f0 + i], wsv[i]);
    }
    __syncthreads();
    if (t < F) {
        atomicAdd(&ssum2[t], red_ss[t]);
        atomicAdd(&wsum2[t], red_ws[t]);
    }
}

// ---------------------------------------------------------------- K2b: all global scalar factors (f64)
__global__ __launch_bounds__(256) void k_scalars(const float* __restrict__ W, const float* __restrict__ a,
                                                 const float* __restrict__ ssum2, const float* __restrict__ wsum2,
                                                 float* __restrict__ s_arr, float* __restrict__ asrc,
                                                 float* __restrict__ adst, double* __restrict__ an_out) {
    int t = threadIdx.x;
    double av = (double)a[t];
    av *= av;
#pragma unroll
    for (int off = 32; off; off >>= 1) av += __shfl_down(av, off, 64);
    __shared__ double wred[4];
    if ((t & 63) == 0) wred[t >> 6] = av;
    __syncthreads();
    double an = fmax(sqrt(wred[0] + wred[1] + wred[2] + wred[3]), MIN_NORM_D);
    if (t == 0) an_out[0] = an;

    if (t < F) {
        double wn2 = 0.0;
        for (int k = 0; k < F; k++) { double w = (double)W[t * F + k]; wn2 += w * w; }
        double wn = fmax(sqrt(wn2), MIN_NORM_D);
        double mxnf = fmax(sqrt((double)ssum2[t]), MIN_NORM_D);
        double tt = tanh(mxnf / wn * atanh_clip(wn));
        double rn = fmax(tt, MIN_NORM_D);
        double pf = (rn > MAXNORM_D) ? MAXNORM_D / rn : 1.0;
        double pn = rn * pf;
        double s = (tt / mxnf) * pf * atanh_clip(pn) / pn;
        s_arr[t] = (float)s;

        double un_s = fmax(s * sqrt((double)DEG * (double)ssum2[t]), MIN_NORM_D);
        double th_s = tanh(un_s);
        double rn2 = fmax(th_s, MIN_NORM_D);
        double pf2 = (rn2 > MAXNORM_D) ? MAXNORM_D / rn2 : 1.0;
        double q_s = s * (th_s / un_s) * pf2;
        asrc[t] = (float)((double)a[t] * q_s);

        double un_d = fmax(s * sqrt((double)wsum2[t]), MIN_NORM_D);
        double th_d = tanh(un_d);
        double rn3 = fmax(th_d, MIN_NORM_D);
        double pf3 = (rn3 > MAXNORM_D) ? MAXNORM_D / rn3 : 1.0;
        double q_d = s * (th_d / un_d) * pf3;
        adst[t] = (float)((double)a[F + t] * q_d);
    }
}

// ---------------------------------------------------------------- K3: P[n]=dot(asrc,y[n,:]) Q[n]=dot(adst,y[n,:])
__global__ __launch_bounds__(256) void k_pq(const float* __restrict__ y, const float* __restrict__ asrc,
                                            const float* __restrict__ adst, float* __restrict__ P,
                                            float* __restrict__ Q, int N) {
    __shared__ float as4[F], ad4[F];
    int t = threadIdx.x;
    if (t < F) { as4[t] = asrc[t]; ad4[t] = adst[t]; }
    __syncthreads();
    int lane = t & 31;
    int n = blockIdx.x * 8 + (t >> 5);
    if (n < N) {
        float4 yv = *(const float4*)&y[(size_t)n * F + lane * 4];
        float4 av = *(const float4*)&as4[lane * 4];
        float4 bv = *(const float4*)&ad4[lane * 4];
        float p = yv.x * av.x + yv.y * av.y + yv.z * av.z + yv.w * av.w;
        float q = yv.x * bv.x + yv.y * bv.y + yv.z * bv.z + yv.w * bv.w;
#pragma unroll
        for (int off = 16; off; off >>= 1) {
            p += __shfl_down(p, off, 32);
            q += __shfl_down(q, off, 32);
        }
        if (lane == 0) { P[n] = p; Q[n] = q; }
    }
}

// ---------------------------------------------------------------- K4: ee_pre[e] = P[src]+Q[dst]; ||ee_pre||^2 (f64)
__global__ __launch_bounds__(256) void k_edge(const int* __restrict__ edge, const float* __restrict__ P,
                                              const float* __restrict__ Q, float* __restrict__ ee_pre,
                                              double* __restrict__ mxn2, int E) {
    int t = threadIdx.x;
    int e = blockIdx.x * 256 + t;
    double local = 0.0;
    if (e < E) {
        int s = edge[e];
        int d = edge[E + e];
        float v = P[s] + Q[d];
        ee_pre[e] = v;
        local = (double)v * (double)v;
    }
#pragma unroll
    for (int off = 32; off; off >>= 1) local += __shfl_down(local, off, 64);
    __shared__ double wsum[4];
    if ((t & 63) == 0) wsum[t >> 6] = local;
    __syncthreads();
    if (t == 0) atomicAdd(mxn2, wsum[0] + wsum[1] + wsum[2] + wsum[3]);
}

// ---------------------------------------------------------------- K6: per-node aggregate + epilogue
// block = 256 threads = 2 node-groups of 128. Edge weights computed ONCE per
// block by threads 0..9 into LDS (the Round-1 profile showed k_agg at 99%
// VALUBusy from 128x-redundant erff/expf per edge).
__global__ __launch_bounds__(256) void k_agg(const int* __restrict__ edge, const float* __restrict__ y,
                                             const float* __restrict__ ee_pre, const float* __restrict__ s_arr,
                                             const double* __restrict__ an_p, const double* __restrict__ mxn2_p,
                                             float* __restrict__ out, int N, int E) {
    __shared__ float wsh[2 * DEG];
    __shared__ int dsh[2 * DEG];
    __shared__ float nrm[4];
    int t = threadIdx.x;
    int n_base = blockIdx.x * 2;

    if (t < 2 * DEG) {
        // each of these 10 threads computes g redundantly (same wave, cheap)
        double an = an_p[0];
        double mxn = fmax(sqrt(mxn2_p[0]), MIN_NORM_D);
        double t2 = tanh(mxn / an * atanh_clip(an));
        double f2 = t2 / mxn;
        double rnp = fmax(t2, MIN_NORM_D);
        double pfp = (rnp > MAXNORM_D) ? MAXNORM_D / rnp : 1.0;
        double pnp = rnp * pfp;
        float g = (float)(f2 * pfp * atanh_clip(pnp) / pnp);

        int n = n_base + t / DEG;
        float w = 0.f; int d = 0;
        if (n < N) {
            int e = n * DEG + (t % DEG);
            d = edge[E + e];
            float xg = g * ee_pre[e];
            float gl = 0.5f * xg * (1.f + erff(xg * 0.70710678f));
            w = expf(-gl);
        }
        wsh[t] = w;
        dsh[t] = d << 7;   // premultiplied row offset (d*F fits in int)
    }
    __syncthreads();

    int grp = t >> 7;        // 0..1
    int f = t & 127;
    int n = n_base + grp;

    float el = 0.f;
    if (n < N) {
        int eb = grp * DEG;
        // broadcast LDS reads (same address across the 128-thread group)
        float w0 = wsh[eb + 0], w1 = wsh[eb + 1], w2 = wsh[eb + 2], w3 = wsh[eb + 3], w4 = wsh[eb + 4];
        int d0 = dsh[eb + 0], d1 = dsh[eb + 1], d2 = dsh[eb + 2], d3 = dsh[eb + 3], d4 = dsh[eb + 4];
        // 5 independent coalesced gathers (512B rows, L2/L3-resident y)
        float y0 = y[d0 + f], y1 = y[d1 + f], y2 = y[d2 + f], y3 = y[d3 + f], y4 = y[d4 + f];
        float rowsum = w0 + w1 + w2 + w3 + w4;
        float accv = w0 * y0;
        accv = fmaf(w1, y1, accv);
        accv = fmaf(w2, y2, accv);
        accv = fmaf(w3, y3, accv);
        accv = fmaf(w4, y4, accv);
        float hp = s_arr[f] * accv / rowsum;
        el = (hp > 0.f) ? hp : expm1f(hp);   // elu
    }
    float ss = el * el;
#pragma unroll
    for (int off = 32; off; off >>= 1) ss += __shfl_down(ss, off, 64);
    if ((t & 63) == 0) nrm[t >> 6] = ss;
    __syncthreads();
    float sum2 = nrm[grp * 2] + nrm[grp * 2 + 1];
    if (n < N) {
        float un = fmaxf(sqrtf(sum2), 1e-15f);
        float th = tanhf(un);
        float sc = th / un;                   // expmap0
        float rn = fmaxf(th, 1e-15f);
        if (rn > 0.996f) sc *= 0.996f / rn;   // proj
        out[(size_t)n * F + f] = el * sc;
    }
}

extern "C" void kernel_launch(void* const* d_in, const int* in_sizes, int n_in,
                              void* d_out, int out_size, void* d_ws, size_t ws_size,
                              hipStream_t stream) {
    const float* x = (const float*)d_in[0];
    const int* edge = (const int*)d_in[1];
    const float* W = (const float*)d_in[2];
    const float* a = (const float*)d_in[3];
    float* out = (float*)d_out;
    int N = in_sizes[0] / F;
    int E = in_sizes[1] / 2;

    char* ws = (char*)d_ws;
    size_t off = 0;
    float* y = (float*)(ws + off);       off += (size_t)N * F * 4;
    float* ee_pre = (float*)(ws + off);  off += (size_t)E * 4;
    float* P = (float*)(ws + off);       off += (size_t)N * 4;
    float* Q = (float*)(ws + off);       off += (size_t)N * 4;
    char* zbase = ws + off;
    int* cnt = (int*)(ws + off);         off += (size_t)N * 4;
    float* ssum2 = (float*)(ws + off);   off += 512;
    float* wsum2 = (float*)(ws + off);   off += 512;
    double* mxn2 = (double*)(ws + off);  off += 8;
    size_t zlen = (size_t)((ws + off) - zbase);
    double* an_p = (double*)(ws + off);  off += 8;
    float* s_arr = (float*)(ws + off);   off += 512;
    float* asrc = (float*)(ws + off);    off += 512;
    float* adst = (float*)(ws + off);    off += 512;

    hipMemsetAsync(zbase, 0, zlen, stream);
    k_hist<<<(E + 255) / 256, 256, 0, stream>>>(edge, cnt, E);
    k_gemm<<<(N + TN - 1) / TN, 256, 0, stream>>>(x, W, cnt, y, ssum2, wsum2, N);
    k_scalars<<<1, 256, 0, stream>>>(W, a, ssum2, wsum2, s_arr, asrc, adst, an_p);
    k_pq<<<(N + 7) / 8, 256, 0, stream>>>(y, asrc, adst, P, Q, N);
    k_edge<<<(E + 255) / 256, 256, 0, stream>>>(edge, P, Q, ee_pre, mxn2, E);
    k_agg<<<(N + 1) / 2, 256, 0, stream>>>(edge, y, ee_pre, s_arr, an_p, mxn2, out, N, E);
}

// Round 3
// 279.961 us; speedup vs baseline: 1.3316x; 1.1723x over previous
//
#include <hip/hip_runtime.h>
#include <math.h>

#define F 128
#define DEG 5
#define TN 64
#define MAXNORM_D 0.996          // (1 - 4e-3)/sqrt(c), c=1
#define MIN_NORM_D 1e-15

__device__ inline double atanh_clip(double v) {
    v = fmin(fmax(v, -1.0 + 1e-7), 1.0 - 1e-7);
    return atanh(v);
}

// ---------------------------------------------------------------- K1: in-degree histogram of dst
__global__ __launch_bounds__(256) void k_hist(const int* __restrict__ edge, int* __restrict__ cnt, int E) {
    int e = blockIdx.x * 256 + threadIdx.x;
    if (e < E) atomicAdd(&cnt[edge[E + e]], 1);
}

// ---------------------------------------------------------------- K2: y = x @ W^T  [N,128]
// Fused: ssum2[f] += sum_n y[n,f]^2 ; wsum2[f] += sum_n cnt[n]*y[n,f]^2
__global__ __launch_bounds__(256) void k_gemm(const float* __restrict__ x, const float* __restrict__ W,
                                              const int* __restrict__ cnt, float* __restrict__ y,
                                              float* __restrict__ ssum2, float* __restrict__ wsum2, int N) {
    __shared__ float WT[64 * 132];   // WT[k][f], padded row 132
    __shared__ float XT[64 * 68];    // XT[k][n], padded row 68
    __shared__ float red_ss[F];
    __shared__ float red_ws[F];
    __shared__ int cntL[TN];

    int t = threadIdx.x;
    int n0 = blockIdx.x * TN;

    if (t < F) { red_ss[t] = 0.f; red_ws[t] = 0.f; }
    if (t < TN) { int n = n0 + t; cntL[t] = (n < N) ? cnt[n] : 0; }

    float4 acc[8];
#pragma unroll
    for (int j = 0; j < 8; j++) acc[j] = make_float4(0.f, 0.f, 0.f, 0.f);

    int f0 = (t & 31) * 4;       // 4 consecutive f
    int nb = (t >> 5) * 8;       // 8 consecutive local n

    for (int kc = 0; kc < F; kc += 64) {
        __syncthreads();
#pragma unroll
        for (int i = 0; i < 8; i++) {
            int id = t + 256 * i;
            int fr = id & 127;
            int kq = id >> 7;   // 0..15
            float4 w4 = *(const float4*)&W[fr * F + kc + kq * 4];
            WT[(kq * 4 + 0) * 132 + fr] = w4.x;
            WT[(kq * 4 + 1) * 132 + fr] = w4.y;
            WT[(kq * 4 + 2) * 132 + fr] = w4.z;
            WT[(kq * 4 + 3) * 132 + fr] = w4.w;
        }
#pragma unroll
        for (int i = 0; i < 4; i++) {
            int id = t + 256 * i;
            int nl = id & 63;
            int kq = id >> 6;   // 0..15
            int n = n0 + nl;
            float4 xv = (n < N) ? *(const float4*)&x[(size_t)n * F + kc + kq * 4]
                                : make_float4(0.f, 0.f, 0.f, 0.f);
            XT[(kq * 4 + 0) * 68 + nl] = xv.x;
            XT[(kq * 4 + 1) * 68 + nl] = xv.y;
            XT[(kq * 4 + 2) * 68 + nl] = xv.z;
            XT[(kq * 4 + 3) * 68 + nl] = xv.w;
        }
        __syncthreads();
#pragma unroll 4
        for (int k = 0; k < 64; k++) {
            float4 w4 = *(const float4*)&WT[k * 132 + f0];
            float4 xa = *(const float4*)&XT[k * 68 + nb];
            float4 xb = *(const float4*)&XT[k * 68 + nb + 4];
#define FMA4(A, S) A.x = fmaf(w4.x, S, A.x); A.y = fmaf(w4.y, S, A.y); \
                   A.z = fmaf(w4.z, S, A.z); A.w = fmaf(w4.w, S, A.w)
            FMA4(acc[0], xa.x); FMA4(acc[1], xa.y); FMA4(acc[2], xa.z); FMA4(acc[3], xa.w);
            FMA4(acc[4], xb.x); FMA4(acc[5], xb.y); FMA4(acc[6], xb.z); FMA4(acc[7], xb.w);
#undef FMA4
        }
    }

#pragma unroll
    for (int j = 0; j < 8; j++) {
        int n = n0 + nb + j;
        if (n < N) *(float4*)&y[(size_t)n * F + f0] = acc[j];
    }
    float ssv[4] = {0.f, 0.f, 0.f, 0.f};
    float wsv[4] = {0.f, 0.f, 0.f, 0.f};
#pragma unroll
    for (int j = 0; j < 8; j++) {
        float c = (float)cntL[nb + j];
        float4 v = acc[j];
        ssv[0] += v.x * v.x; ssv[1] += v.y * v.y; ssv[2] += v.z * v.z; ssv[3] += v.w * v.w;
        wsv[0] += c * v.x * v.x; wsv[1] += c * v.y * v.y; wsv[2] += c * v.z * v.z; wsv[3] += c * v.w * v.w;
    }
#pragma unroll
    for (int i = 0; i < 4; i++) {
        atomicAdd(&red_ss[f0 + i], ssv[i]);
        atomicAdd(&red_ws[f0 + i], wsv[i]);
    }
    __syncthreads();
    if (t < F) {
        atomicAdd(&ssum2[t], red_ss[t]);
        atomicAdd(&wsum2[t], red_ws[t]);
    }
}

// ---------------------------------------------------------------- K2b: all global scalar factors (f64)
__global__ __launch_bounds__(256) void k_scalars(const float* __restrict__ W, const float* __restrict__ a,
                                                 const float* __restrict__ ssum2, const float* __restrict__ wsum2,
                                                 float* __restrict__ s_arr, float* __restrict__ asrc,
                                                 float* __restrict__ adst, double* __restrict__ an_out) {
    int t = threadIdx.x;
    double av = (double)a[t];
    av *= av;
#pragma unroll
    for (int off = 32; off; off >>= 1) av += __shfl_down(av, off, 64);
    __shared__ double wred[4];
    if ((t & 63) == 0) wred[t >> 6] = av;
    __syncthreads();
    double an = fmax(sqrt(wred[0] + wred[1] + wred[2] + wred[3]), MIN_NORM_D);
    if (t == 0) an_out[0] = an;

    if (t < F) {
        double wn2 = 0.0;
        for (int k = 0; k < F; k++) { double w = (double)W[t * F + k]; wn2 += w * w; }
        double wn = fmax(sqrt(wn2), MIN_NORM_D);
        double mxnf = fmax(sqrt((double)ssum2[t]), MIN_NORM_D);
        double tt = tanh(mxnf / wn * atanh_clip(wn));
        double rn = fmax(tt, MIN_NORM_D);
        double pf = (rn > MAXNORM_D) ? MAXNORM_D / rn : 1.0;
        double pn = rn * pf;
        double s = (tt / mxnf) * pf * atanh_clip(pn) / pn;
        s_arr[t] = (float)s;

        double un_s = fmax(s * sqrt((double)DEG * (double)ssum2[t]), MIN_NORM_D);
        double th_s = tanh(un_s);
        double rn2 = fmax(th_s, MIN_NORM_D);
        double pf2 = (rn2 > MAXNORM_D) ? MAXNORM_D / rn2 : 1.0;
        double q_s = s * (th_s / un_s) * pf2;
        asrc[t] = (float)((double)a[t] * q_s);

        double un_d = fmax(s * sqrt((double)wsum2[t]), MIN_NORM_D);
        double th_d = tanh(un_d);
        double rn3 = fmax(th_d, MIN_NORM_D);
        double pf3 = (rn3 > MAXNORM_D) ? MAXNORM_D / rn3 : 1.0;
        double q_d = s * (th_d / un_d) * pf3;
        adst[t] = (float)((double)a[F + t] * q_d);
    }
}

// ---------------------------------------------------------------- K3: P[n]=dot(asrc,y[n,:]) Q[n]=dot(adst,y[n,:])
__global__ __launch_bounds__(256) void k_pq(const float* __restrict__ y, const float* __restrict__ asrc,
                                            const float* __restrict__ adst, float* __restrict__ P,
                                            float* __restrict__ Q, int N) {
    __shared__ float as4[F], ad4[F];
    int t = threadIdx.x;
    if (t < F) { as4[t] = asrc[t]; ad4[t] = adst[t]; }
    __syncthreads();
    int lane = t & 31;
    int n = blockIdx.x * 8 + (t >> 5);
    if (n < N) {
        float4 yv = *(const float4*)&y[(size_t)n * F + lane * 4];
        float4 av = *(const float4*)&as4[lane * 4];
        float4 bv = *(const float4*)&ad4[lane * 4];
        float p = yv.x * av.x + yv.y * av.y + yv.z * av.z + yv.w * av.w;
        float q = yv.x * bv.x + yv.y * bv.y + yv.z * bv.z + yv.w * bv.w;
#pragma unroll
        for (int off = 16; off; off >>= 1) {
            p += __shfl_down(p, off, 32);
            q += __shfl_down(q, off, 32);
        }
        if (lane == 0) { P[n] = p; Q[n] = q; }
    }
}

// ---------------------------------------------------------------- K4: ee_pre[e] = P[src]+Q[dst]; ||ee_pre||^2 (f64)
__global__ __launch_bounds__(256) void k_edge(const int* __restrict__ edge, const float* __restrict__ P,
                                              const float* __restrict__ Q, float* __restrict__ ee_pre,
                                              double* __restrict__ mxn2, int E) {
    int t = threadIdx.x;
    int e = blockIdx.x * 256 + t;
    double local = 0.0;
    if (e < E) {
        int s = edge[e];
        int d = edge[E + e];
        float v = P[s] + Q[d];
        ee_pre[e] = v;
        local = (double)v * (double)v;
    }
#pragma unroll
    for (int off = 32; off; off >>= 1) local += __shfl_down(local, off, 64);
    __shared__ double wsum[4];
    if ((t & 63) == 0) wsum[t >> 6] = local;
    __syncthreads();
    if (t == 0) atomicAdd(mxn2, wsum[0] + wsum[1] + wsum[2] + wsum[3]);
}

// ---------------------------------------------------------------- K5: per-node NORMALIZED edge weights
// wn[n*DEG+j] = w_j / sum_j w_j,  w_j = exp(-gelu(g * ee_pre)).  The f64 g-chain
// runs once per block (391 blocks), not once per node-pair (was 50k blocks in k_agg).
__global__ __launch_bounds__(256) void k_w(const float* __restrict__ ee_pre,
                                           const double* __restrict__ an_p, const double* __restrict__ mxn2_p,
                                           float* __restrict__ wn, int N) {
    __shared__ float gS;
    if (threadIdx.x == 0) {
        double an = an_p[0];
        double mxn = fmax(sqrt(mxn2_p[0]), MIN_NORM_D);
        double t2 = tanh(mxn / an * atanh_clip(an));
        double f2 = t2 / mxn;
        double rnp = fmax(t2, MIN_NORM_D);
        double pfp = (rnp > MAXNORM_D) ? MAXNORM_D / rnp : 1.0;
        double pnp = rnp * pfp;
        gS = (float)(f2 * pfp * atanh_clip(pnp) / pnp);
    }
    __syncthreads();
    float g = gS;
    int n = blockIdx.x * 256 + threadIdx.x;
    if (n < N) {
        float r[DEG];
        float rowsum = 0.f;
#pragma unroll
        for (int j = 0; j < DEG; j++) {
            float xg = g * ee_pre[n * DEG + j];
            float gl = 0.5f * xg * (1.f + erff(xg * 0.70710678f));
            float w = expf(-gl);
            r[j] = w;
            rowsum += w;
        }
        float inv = 1.f / rowsum;
#pragma unroll
        for (int j = 0; j < DEG; j++) wn[n * DEG + j] = r[j] * inv;
    }
}

// ---------------------------------------------------------------- K6: per-node aggregate + epilogue
// 32 lanes x float4 per node, 8 nodes per 256-block. Pure gather+FMA; weights
// pre-normalized by k_w (no division, no transcendental weight math here).
__global__ __launch_bounds__(256) void k_agg(const int* __restrict__ edge, const float* __restrict__ y,
                                             const float* __restrict__ wn, const float* __restrict__ s_arr,
                                             float* __restrict__ out, int N, int E) {
    __shared__ float wsh[8 * DEG];
    __shared__ int dsh[8 * DEG];
    int t = threadIdx.x;
    int n_base = blockIdx.x * 8;

    if (t < 8 * DEG) {
        int n = n_base + t / DEG;
        float w = 0.f; int d = 0;
        if (n < N) {
            int e = n * DEG + (t % DEG);
            w = wn[e];
            d = edge[E + e];
        }
        wsh[t] = w;
        dsh[t] = d << 7;   // premultiplied row offset (d*F fits in int)
    }
    __syncthreads();

    int grp = t >> 5;        // 0..7
    int lane = t & 31;
    int n = n_base + grp;
    if (n >= N) return;

    int fo = lane * 4;
    float4 acc = make_float4(0.f, 0.f, 0.f, 0.f);
#pragma unroll
    for (int j = 0; j < DEG; j++) {
        float w = wsh[grp * DEG + j];          // broadcast LDS read
        int d = dsh[grp * DEG + j];
        float4 yv = *(const float4*)&y[d + fo];
        acc.x = fmaf(w, yv.x, acc.x);
        acc.y = fmaf(w, yv.y, acc.y);
        acc.z = fmaf(w, yv.z, acc.z);
        acc.w = fmaf(w, yv.w, acc.w);
    }
    float4 s4 = *(const float4*)&s_arr[fo];
    float4 el;
    float hx = s4.x * acc.x; el.x = (hx > 0.f) ? hx : expm1f(hx);
    float hy = s4.y * acc.y; el.y = (hy > 0.f) ? hy : expm1f(hy);
    float hz = s4.z * acc.z; el.z = (hz > 0.f) ? hz : expm1f(hz);
    float hw = s4.w * acc.w; el.w = (hw > 0.f) ? hw : expm1f(hw);

    float ss = el.x * el.x + el.y * el.y + el.z * el.z + el.w * el.w;
#pragma unroll
    for (int off = 16; off; off >>= 1) ss += __shfl_xor(ss, off, 32);   // all lanes get total

    float un = fmaxf(sqrtf(ss), 1e-15f);
    float th = tanhf(un);
    float sc = th / un;                   // expmap0
    float rn = fmaxf(th, 1e-15f);
    if (rn > 0.996f) sc *= 0.996f / rn;   // proj
    float4 o = make_float4(el.x * sc, el.y * sc, el.z * sc, el.w * sc);
    *(float4*)&out[(size_t)n * F + fo] = o;
}

extern "C" void kernel_launch(void* const* d_in, const int* in_sizes, int n_in,
                              void* d_out, int out_size, void* d_ws, size_t ws_size,
                              hipStream_t stream) {
    const float* x = (const float*)d_in[0];
    const int* edge = (const int*)d_in[1];
    const float* W = (const float*)d_in[2];
    const float* a = (const float*)d_in[3];
    float* out = (float*)d_out;
    int N = in_sizes[0] / F;
    int E = in_sizes[1] / 2;

    char* ws = (char*)d_ws;
    size_t off = 0;
    float* y = (float*)(ws + off);       off += (size_t)N * F * 4;
    float* ee_pre = (float*)(ws + off);  off += (size_t)E * 4;
    float* wn = (float*)(ws + off);      off += (size_t)E * 4;
    float* P = (float*)(ws + off);       off += (size_t)N * 4;
    float* Q = (float*)(ws + off);       off += (size_t)N * 4;
    char* zbase = ws + off;
    int* cnt = (int*)(ws + off);         off += (size_t)N * 4;
    float* ssum2 = (float*)(ws + off);   off += 512;
    float* wsum2 = (float*)(ws + off);   off += 512;
    double* mxn2 = (double*)(ws + off);  off += 8;
    size_t zlen = (size_t)((ws + off) - zbase);
    double* an_p = (double*)(ws + off);  off += 8;
    float* s_arr = (float*)(ws + off);   off += 512;
    float* asrc = (float*)(ws + off);    off += 512;
    float* adst = (float*)(ws + off);    off += 512;

    hipMemsetAsync(zbase, 0, zlen, stream);
    k_hist<<<(E + 255) / 256, 256, 0, stream>>>(edge, cnt, E);
    k_gemm<<<(N + TN - 1) / TN, 256, 0, stream>>>(x, W, cnt, y, ssum2, wsum2, N);
    k_scalars<<<1, 256, 0, stream>>>(W, a, ssum2, wsum2, s_arr, asrc, adst, an_p);
    k_pq<<<(N + 7) / 8, 256, 0, stream>>>(y, asrc, adst, P, Q, N);
    k_edge<<<(E + 255) / 256, 256, 0, stream>>>(edge, P, Q, ee_pre, mxn2, E);
    k_w<<<(N + 255) / 256, 256, 0, stream>>>(ee_pre, an_p, mxn2, wn, N);
    k_agg<<<(N + 7) / 8, 256, 0, stream>>>(edge, y, wn, s_arr, out, N, E);
}

// Round 4
// 278.428 us; speedup vs baseline: 1.3389x; 1.0055x over previous
//
#include <hip/hip_runtime.h>
#include <math.h>

#define F 128
#define DEG 5
#define TN 64
#define MAXNORM_D 0.996          // (1 - 4e-3)/sqrt(c), c=1
#define MIN_NORM_D 1e-15

__device__ inline double atanh_clip(double v) {
    v = fmin(fmax(v, -1.0 + 1e-7), 1.0 - 1e-7);
    return atanh(v);
}

__device__ inline void load_lds16(const void* g, void* l) {
    __builtin_amdgcn_global_load_lds((const __attribute__((address_space(1))) void*)g,
                                     (__attribute__((address_space(3))) void*)l, 16, 0, 0);
}

// ---------------------------------------------------------------- K0: WT[k][f] = W[f][k] (once, 64 KB)
__global__ __launch_bounds__(256) void k_wt(const float* __restrict__ W, float* __restrict__ WT) {
    int t = blockIdx.x * 256 + threadIdx.x;   // 4096 threads, one float4 of W each
    int f = t >> 5;
    int k4 = (t & 31) * 4;
    float4 w = *(const float4*)&W[f * F + k4];
    WT[(k4 + 0) * F + f] = w.x;
    WT[(k4 + 1) * F + f] = w.y;
    WT[(k4 + 2) * F + f] = w.z;
    WT[(k4 + 3) * F + f] = w.w;
}

// ---------------------------------------------------------------- K1: in-degree histogram of dst
__global__ __launch_bounds__(256) void k_hist(const int* __restrict__ edge, int* __restrict__ cnt, int E) {
    int e = blockIdx.x * 256 + threadIdx.x;
    if (e < E) atomicAdd(&cnt[edge[E + e]], 1);
}

// ---------------------------------------------------------------- K2: y = x @ W^T  [N,128]
// Staging via global_load_lds (16B) — no transposes, no scalar LDS writes.
// Ws[k][f] from pre-transposed WT (contiguous 32KB chunk); Xs[n][k] natural.
// Fused: ssum2[f] += sum_n y[n,f]^2 ; wsum2[f] += sum_n cnt[n]*y[n,f]^2
__global__ __launch_bounds__(256) void k_gemm(const float* __restrict__ x, const float* __restrict__ WT,
                                              const int* __restrict__ cnt, float* __restrict__ y,
                                              float* __restrict__ ssum2, float* __restrict__ wsum2, int N) {
    __shared__ float Ws[64 * F];    // [k][f]  32 KB
    __shared__ float Xs[TN * 64];   // [n][k]  16 KB, rows 256B
    __shared__ float red_ss[F];
    __shared__ float red_ws[F];
    __shared__ int cntL[TN];

    int t = threadIdx.x;
    int n0 = blockIdx.x * TN;
    int lane = t & 63;
    int wv = t >> 6;

    if (t < F) { red_ss[t] = 0.f; red_ws[t] = 0.f; }
    if (t < TN) { int n = n0 + t; cntL[t] = (n < N) ? cnt[n] : 0; }

    float4 acc[8];
#pragma unroll
    for (int j = 0; j < 8; j++) acc[j] = make_float4(0.f, 0.f, 0.f, 0.f);

    int f0 = (t & 31) * 4;       // 4 consecutive f
    int nb = (t >> 5) * 8;       // 8 consecutive local n

    for (int kc = 0; kc < F; kc += 64) {
        __syncthreads();
        // stage W chunk: WT rows kc..kc+63 are one contiguous 32 KB region
        {
            const char* wsrc = (const char*)(WT + kc * F);
            char* wdst = (char*)Ws;
#pragma unroll
            for (int r = 0; r < 8; r++) {
                int off = wv * 8192 + r * 1024 + lane * 16;
                load_lds16(wsrc + off, wdst + off);
            }
        }
        // stage X chunk: 64 rows x 256B; per-lane global gather, lane-contiguous LDS
        {
#pragma unroll
            for (int r = 0; r < 4; r++) {
                int off = wv * 4096 + r * 1024 + lane * 16;
                int row = off >> 8;
                int col = off & 255;
                int rn = n0 + row; if (rn > N - 1) rn = N - 1;   // clamp: no fault, masked later
                load_lds16((const char*)x + (size_t)rn * 512 + kc * 4 + col, (char*)Xs + off);
            }
        }
        __syncthreads();
#pragma unroll 2
        for (int k4 = 0; k4 < 64; k4 += 4) {
            float4 w0 = *(const float4*)&Ws[(k4 + 0) * F + f0];
            float4 w1 = *(const float4*)&Ws[(k4 + 1) * F + f0];
            float4 w2 = *(const float4*)&Ws[(k4 + 2) * F + f0];
            float4 w3 = *(const float4*)&Ws[(k4 + 3) * F + f0];
#pragma unroll
            for (int j = 0; j < 8; j++) {
                float4 xv = *(const float4*)&Xs[(nb + j) * 64 + k4];
                acc[j].x = fmaf(xv.x, w0.x, acc[j].x); acc[j].y = fmaf(xv.x, w0.y, acc[j].y);
                acc[j].z = fmaf(xv.x, w0.z, acc[j].z); acc[j].w = fmaf(xv.x, w0.w, acc[j].w);
                acc[j].x = fmaf(xv.y, w1.x, acc[j].x); acc[j].y = fmaf(xv.y, w1.y, acc[j].y);
                acc[j].z = fmaf(xv.y, w1.z, acc[j].z); acc[j].w = fmaf(xv.y, w1.w, acc[j].w);
                acc[j].x = fmaf(xv.z, w2.x, acc[j].x); acc[j].y = fmaf(xv.z, w2.y, acc[j].y);
                acc[j].z = fmaf(xv.z, w2.z, acc[j].z); acc[j].w = fmaf(xv.z, w2.w, acc[j].w);
                acc[j].x = fmaf(xv.w, w3.x, acc[j].x); acc[j].y = fmaf(xv.w, w3.y, acc[j].y);
                acc[j].z = fmaf(xv.w, w3.z, acc[j].z); acc[j].w = fmaf(xv.w, w3.w, acc[j].w);
            }
        }
    }

#pragma unroll
    for (int j = 0; j < 8; j++) {
        int n = n0 + nb + j;
        if (n < N) *(float4*)&y[(size_t)n * F + f0] = acc[j];
    }
    float ssv[4] = {0.f, 0.f, 0.f, 0.f};
    float wsv[4] = {0.f, 0.f, 0.f, 0.f};
#pragma unroll
    for (int j = 0; j < 8; j++) {
        float valid = (n0 + nb + j < N) ? 1.f : 0.f;   // OOB rows hold clamped garbage
        float c = (float)cntL[nb + j];
        float4 v = acc[j];
        ssv[0] += valid * v.x * v.x; ssv[1] += valid * v.y * v.y;
        ssv[2] += valid * v.z * v.z; ssv[3] += valid * v.w * v.w;
        wsv[0] += c * v.x * v.x; wsv[1] += c * v.y * v.y;
        wsv[2] += c * v.z * v.z; wsv[3] += c * v.w * v.w;
    }
#pragma unroll
    for (int i = 0; i < 4; i++) {
        atomicAdd(&red_ss[f0 + i], ssv[i]);
        atomicAdd(&red_ws[f0 + i], wsv[i]);
    }
    __syncthreads();
    if (t < F) {
        atomicAdd(&ssum2[t], red_ss[t]);
        atomicAdd(&wsum2[t], red_ws[t]);
    }
}

// ---------------------------------------------------------------- K2b: all global scalar factors (f64)
__global__ __launch_bounds__(256) void k_scalars(const float* __restrict__ W, const float* __restrict__ a,
                                                 const float* __restrict__ ssum2, const float* __restrict__ wsum2,
                                                 float* __restrict__ s_arr, float* __restrict__ asrc,
                                                 float* __restrict__ adst, double* __restrict__ an_out) {
    int t = threadIdx.x;
    double av = (double)a[t];
    av *= av;
#pragma unroll
    for (int off = 32; off; off >>= 1) av += __shfl_down(av, off, 64);
    __shared__ double wred[4];
    if ((t & 63) == 0) wred[t >> 6] = av;
    __syncthreads();
    double an = fmax(sqrt(wred[0] + wred[1] + wred[2] + wred[3]), MIN_NORM_D);
    if (t == 0) an_out[0] = an;

    if (t < F) {
        double wn2 = 0.0;
        for (int k = 0; k < F; k++) { double w = (double)W[t * F + k]; wn2 += w * w; }
        double wn = fmax(sqrt(wn2), MIN_NORM_D);
        double mxnf = fmax(sqrt((double)ssum2[t]), MIN_NORM_D);
        double tt = tanh(mxnf / wn * atanh_clip(wn));
        double rn = fmax(tt, MIN_NORM_D);
        double pf = (rn > MAXNORM_D) ? MAXNORM_D / rn : 1.0;
        double pn = rn * pf;
        double s = (tt / mxnf) * pf * atanh_clip(pn) / pn;
        s_arr[t] = (float)s;

        double un_s = fmax(s * sqrt((double)DEG * (double)ssum2[t]), MIN_NORM_D);
        double th_s = tanh(un_s);
        double rn2 = fmax(th_s, MIN_NORM_D);
        double pf2 = (rn2 > MAXNORM_D) ? MAXNORM_D / rn2 : 1.0;
        double q_s = s * (th_s / un_s) * pf2;
        asrc[t] = (float)((double)a[t] * q_s);

        double un_d = fmax(s * sqrt((double)wsum2[t]), MIN_NORM_D);
        double th_d = tanh(un_d);
        double rn3 = fmax(th_d, MIN_NORM_D);
        double pf3 = (rn3 > MAXNORM_D) ? MAXNORM_D / rn3 : 1.0;
        double q_d = s * (th_d / un_d) * pf3;
        adst[t] = (float)((double)a[F + t] * q_d);
    }
}

// ---------------------------------------------------------------- K3: P[n]=dot(asrc,y[n,:]) Q[n]=dot(adst,y[n,:])
__global__ __launch_bounds__(256) void k_pq(const float* __restrict__ y, const float* __restrict__ asrc,
                                            const float* __restrict__ adst, float* __restrict__ P,
                                            float* __restrict__ Q, int N) {
    __shared__ float as4[F], ad4[F];
    int t = threadIdx.x;
    if (t < F) { as4[t] = asrc[t]; ad4[t] = adst[t]; }
    __syncthreads();
    int lane = t & 31;
    int n = blockIdx.x * 8 + (t >> 5);
    if (n < N) {
        float4 yv = *(const float4*)&y[(size_t)n * F + lane * 4];
        float4 av = *(const float4*)&as4[lane * 4];
        float4 bv = *(const float4*)&ad4[lane * 4];
        float p = yv.x * av.x + yv.y * av.y + yv.z * av.z + yv.w * av.w;
        float q = yv.x * bv.x + yv.y * bv.y + yv.z * bv.z + yv.w * bv.w;
#pragma unroll
        for (int off = 16; off; off >>= 1) {
            p += __shfl_down(p, off, 32);
            q += __shfl_down(q, off, 32);
        }
        if (lane == 0) { P[n] = p; Q[n] = q; }
    }
}

// ---------------------------------------------------------------- K4: ee_pre[e] = P[src]+Q[dst]; ||ee_pre||^2 (f64)
__global__ __launch_bounds__(256) void k_edge(const int* __restrict__ edge, const float* __restrict__ P,
                                              const float* __restrict__ Q, float* __restrict__ ee_pre,
                                              double* __restrict__ mxn2, int E) {
    int t = threadIdx.x;
    int e = blockIdx.x * 256 + t;
    double local = 0.0;
    if (e < E) {
        int s = edge[e];
        int d = edge[E + e];
        float v = P[s] + Q[d];
        ee_pre[e] = v;
        local = (double)v * (double)v;
    }
#pragma unroll
    for (int off = 32; off; off >>= 1) local += __shfl_down(local, off, 64);
    __shared__ double wsum[4];
    if ((t & 63) == 0) wsum[t >> 6] = local;
    __syncthreads();
    if (t == 0) atomicAdd(mxn2, wsum[0] + wsum[1] + wsum[2] + wsum[3]);
}

// ---------------------------------------------------------------- K5: per-node NORMALIZED edge weights
__global__ __launch_bounds__(256) void k_w(const float* __restrict__ ee_pre,
                                           const double* __restrict__ an_p, const double* __restrict__ mxn2_p,
                                           float* __restrict__ wn, int N) {
    __shared__ float gS;
    if (threadIdx.x == 0) {
        double an = an_p[0];
        double mxn = fmax(sqrt(mxn2_p[0]), MIN_NORM_D);
        double t2 = tanh(mxn / an * atanh_clip(an));
        double f2 = t2 / mxn;
        double rnp = fmax(t2, MIN_NORM_D);
        double pfp = (rnp > MAXNORM_D) ? MAXNORM_D / rnp : 1.0;
        double pnp = rnp * pfp;
        gS = (float)(f2 * pfp * atanh_clip(pnp) / pnp);
    }
    __syncthreads();
    float g = gS;
    int n = blockIdx.x * 256 + threadIdx.x;
    if (n < N) {
        float r[DEG];
        float rowsum = 0.f;
#pragma unroll
        for (int j = 0; j < DEG; j++) {
            float xg = g * ee_pre[n * DEG + j];
            float gl = 0.5f * xg * (1.f + erff(xg * 0.70710678f));
            float w = expf(-gl);
            r[j] = w;
            rowsum += w;
        }
        float inv = 1.f / rowsum;
#pragma unroll
        for (int j = 0; j < DEG; j++) wn[n * DEG + j] = r[j] * inv;
    }
}

// ---------------------------------------------------------------- K6: per-node aggregate + epilogue
__global__ __launch_bounds__(256) void k_agg(const int* __restrict__ edge, const float* __restrict__ y,
                                             const float* __restrict__ wn, const float* __restrict__ s_arr,
                                             float* __restrict__ out, int N, int E) {
    __shared__ float wsh[8 * DEG];
    __shared__ int dsh[8 * DEG];
    int t = threadIdx.x;
    int n_base = blockIdx.x * 8;

    if (t < 8 * DEG) {
        int n = n_base + t / DEG;
        float w = 0.f; int d = 0;
        if (n < N) {
            int e = n * DEG + (t % DEG);
            w = wn[e];
            d = edge[E + e];
        }
        wsh[t] = w;
        dsh[t] = d << 7;
    }
    __syncthreads();

    int grp = t >> 5;        // 0..7
    int lane = t & 31;
    int n = n_base + grp;
    if (n >= N) return;

    int fo = lane * 4;
    float4 acc = make_float4(0.f, 0.f, 0.f, 0.f);
#pragma unroll
    for (int j = 0; j < DEG; j++) {
        float w = wsh[grp * DEG + j];
        int d = dsh[grp * DEG + j];
        float4 yv = *(const float4*)&y[d + fo];
        acc.x = fmaf(w, yv.x, acc.x);
        acc.y = fmaf(w, yv.y, acc.y);
        acc.z = fmaf(w, yv.z, acc.z);
        acc.w = fmaf(w, yv.w, acc.w);
    }
    float4 s4 = *(const float4*)&s_arr[fo];
    float4 el;
    float hx = s4.x * acc.x; el.x = (hx > 0.f) ? hx : expm1f(hx);
    float hy = s4.y * acc.y; el.y = (hy > 0.f) ? hy : expm1f(hy);
    float hz = s4.z * acc.z; el.z = (hz > 0.f) ? hz : expm1f(hz);
    float hw = s4.w * acc.w; el.w = (hw > 0.f) ? hw : expm1f(hw);

    float ss = el.x * el.x + el.y * el.y + el.z * el.z + el.w * el.w;
#pragma unroll
    for (int off = 16; off; off >>= 1) ss += __shfl_xor(ss, off, 32);

    float un = fmaxf(sqrtf(ss), 1e-15f);
    float th = tanhf(un);
    float sc = th / un;                   // expmap0
    float rn = fmaxf(th, 1e-15f);
    if (rn > 0.996f) sc *= 0.996f / rn;   // proj
    float4 o = make_float4(el.x * sc, el.y * sc, el.z * sc, el.w * sc);
    *(float4*)&out[(size_t)n * F + fo] = o;
}

extern "C" void kernel_launch(void* const* d_in, const int* in_sizes, int n_in,
                              void* d_out, int out_size, void* d_ws, size_t ws_size,
                              hipStream_t stream) {
    const float* x = (const float*)d_in[0];
    const int* edge = (const int*)d_in[1];
    const float* W = (const float*)d_in[2];
    const float* a = (const float*)d_in[3];
    float* out = (float*)d_out;
    int N = in_sizes[0] / F;
    int E = in_sizes[1] / 2;

    char* ws = (char*)d_ws;
    size_t off = 0;
    float* y = (float*)(ws + off);       off += (size_t)N * F * 4;
    float* WT = (float*)(ws + off);      off += (size_t)F * F * 4;   // 16B-aligned
    float* ee_pre = (float*)(ws + off);  off += (size_t)E * 4;
    float* wn = (float*)(ws + off);      off += (size_t)E * 4;
    float* P = (float*)(ws + off);       off += (size_t)N * 4;
    float* Q = (float*)(ws + off);       off += (size_t)N * 4;
    char* zbase = ws + off;
    int* cnt = (int*)(ws + off);         off += (size_t)N * 4;
    float* ssum2 = (float*)(ws + off);   off += 512;
    float* wsum2 = (float*)(ws + off);   off += 512;
    double* mxn2 = (double*)(ws + off);  off += 8;
    size_t zlen = (size_t)((ws + off) - zbase);
    double* an_p = (double*)(ws + off);  off += 8;
    float* s_arr = (float*)(ws + off);   off += 512;
    float* asrc = (float*)(ws + off);    off += 512;
    float* adst = (float*)(ws + off);    off += 512;

    hipMemsetAsync(zbase, 0, zlen, stream);
    k_wt<<<16, 256, 0, stream>>>(W, WT);
    k_hist<<<(E + 255) / 256, 256, 0, stream>>>(edge, cnt, E);
    k_gemm<<<(N + TN - 1) / TN, 256, 0, stream>>>(x, WT, cnt, y, ssum2, wsum2, N);
    k_scalars<<<1, 256, 0, stream>>>(W, a, ssum2, wsum2, s_arr, asrc, adst, an_p);
    k_pq<<<(N + 7) / 8, 256, 0, stream>>>(y, asrc, adst, P, Q, N);
    k_edge<<<(E + 255) / 256, 256, 0, stream>>>(edge, P, Q, ee_pre, mxn2, E);
    k_w<<<(N + 255) / 256, 256, 0, stream>>>(ee_pre, an_p, mxn2, wn, N);
    k_agg<<<(N + 7) / 8, 256, 0, stream>>>(edge, y, wn, s_arr, out, N, E);
}